// Round 1
// baseline (650.373 us; speedup 1.0000x reference)
//
#include <hip/hip_runtime.h>
#include <hip/hip_bf16.h>
#include <math.h>

#define NN 50000
#define EE 250000

// ---------- workspace layout (floats) ----------
// h:   NN*64
// q:   NN*256
// k:   NN*256
// v:   NN*256
// xr:  NN*64
// agg: NN*64   (zeroed per layer)
// s:   NN*4    (zeroed per layer, contiguous with agg)
// ex:  EE*4
#define OFF_H   ((size_t)0)
#define OFF_Q   (OFF_H + (size_t)NN * 64)
#define OFF_K   (OFF_Q + (size_t)NN * 256)
#define OFF_V   (OFF_K + (size_t)NN * 256)
#define OFF_XR  (OFF_V + (size_t)NN * 256)
#define OFF_AGG (OFF_XR + (size_t)NN * 64)
#define OFF_S   (OFF_AGG + (size_t)NN * 64)
#define OFF_EX  (OFF_S + (size_t)NN * 4)

__device__ __forceinline__ float wsum64(float v) {
  v += __shfl_xor(v, 1, 64);
  v += __shfl_xor(v, 2, 64);
  v += __shfl_xor(v, 4, 64);
  v += __shfl_xor(v, 8, 64);
  v += __shfl_xor(v, 16, 64);
  v += __shfl_xor(v, 32, 64);
  return v;
}

__device__ __forceinline__ float gelu_exact(float a) {
  return 0.5f * a * (1.0f + erff(a * 0.70710678118654752f));
}

// ---------------- encoder: h = LN(gelu(x@W1+b1)) @ W2 + b2 ----------------
// one wave per node, lane = output channel
__global__ __launch_bounds__(256) void enc_kernel(
    const float* __restrict__ x, const float* __restrict__ w1,
    const float* __restrict__ b1, const float* __restrict__ lg,
    const float* __restrict__ lb, const float* __restrict__ w2,
    const float* __restrict__ b2, float* __restrict__ h) {
  const int t = blockIdx.x * 256 + threadIdx.x;
  const int node = t >> 6;
  const int lane = t & 63;
  const int wib = (threadIdx.x >> 6);
  __shared__ float gS[4][64];
  if (node < NN) {
    float a = b1[lane];
    #pragma unroll
    for (int d = 0; d < 6; d++) a += x[(size_t)node * 6 + d] * w1[d * 64 + lane];
    float g = gelu_exact(a);
    float s1 = wsum64(g);
    float s2 = wsum64(g * g);
    float m = s1 * (1.0f / 64.0f);
    float var = s2 * (1.0f / 64.0f) - m * m;
    g = (g - m) * rsqrtf(var + 1e-5f) * lg[lane] + lb[lane];
    gS[wib][lane] = g;
  }
  __syncthreads();
  if (node < NN) {
    float a = b2[lane];
    #pragma unroll 8
    for (int d = 0; d < 64; d++) a += gS[wib][d] * w2[d * 64 + lane];
    h[(size_t)node * 64 + lane] = a;
  }
}

// ---------------- fused projections: q,k,v [N,256], xr [N,64] ----------------
// block = 256 threads handles 16 nodes; h tile staged transposed in LDS.
#define FMA16(A, W) do { \
  A[0]+=h0.x*(W); A[1]+=h0.y*(W); A[2]+=h0.z*(W); A[3]+=h0.w*(W); \
  A[4]+=h1.x*(W); A[5]+=h1.y*(W); A[6]+=h1.z*(W); A[7]+=h1.w*(W); \
  A[8]+=h2.x*(W); A[9]+=h2.y*(W); A[10]+=h2.z*(W); A[11]+=h2.w*(W); \
  A[12]+=h3.x*(W); A[13]+=h3.y*(W); A[14]+=h3.z*(W); A[15]+=h3.w*(W); } while (0)

__global__ __launch_bounds__(256) void proj_kernel(
    const float* __restrict__ h,
    const float* __restrict__ Wq, const float* __restrict__ bq,
    const float* __restrict__ Wk, const float* __restrict__ bk,
    const float* __restrict__ Wv, const float* __restrict__ bv,
    const float* __restrict__ Ws, const float* __restrict__ bs,
    float* __restrict__ q, float* __restrict__ k, float* __restrict__ v,
    float* __restrict__ xr) {
  __shared__ __align__(16) float hS[64][20];  // pad 20 -> 16B-aligned rows
  const int n0 = blockIdx.x * 16;
  const int t = threadIdx.x;
  #pragma unroll
  for (int i = 0; i < 4; i++) {
    int idx = t + i * 256;
    int node = idx >> 6, d = idx & 63;
    hS[d][node] = h[(size_t)(n0 + node) * 64 + d];
  }
  __syncthreads();

  float aq[16], ak[16], av[16];
  #pragma unroll
  for (int n = 0; n < 16; n++) { aq[n] = 0.f; ak[n] = 0.f; av[n] = 0.f; }
  float ax0 = 0.f, ax1 = 0.f, ax2 = 0.f, ax3 = 0.f;
  const int wq_ = t >> 6;  // wave-uniform quad selector for xr
  const int cs = t & 63;   // xr column

  for (int d = 0; d < 64; d++) {
    const float4* hp = reinterpret_cast<const float4*>(&hS[d][0]);
    float4 h0 = hp[0], h1 = hp[1], h2 = hp[2], h3 = hp[3];
    float wqv = Wq[d * 256 + t];
    float wkv = Wk[d * 256 + t];
    float wvv = Wv[d * 256 + t];
    float wsv = Ws[d * 64 + cs];
    FMA16(aq, wqv);
    FMA16(ak, wkv);
    FMA16(av, wvv);
    float4 hx = (wq_ == 0) ? h0 : (wq_ == 1) ? h1 : (wq_ == 2) ? h2 : h3;
    ax0 += hx.x * wsv; ax1 += hx.y * wsv; ax2 += hx.z * wsv; ax3 += hx.w * wsv;
  }

  float bqv = bq[t], bkv = bk[t], bvv = bv[t];
  #pragma unroll
  for (int n = 0; n < 16; n++) {
    size_t base = (size_t)(n0 + n) * 256 + t;
    q[base] = aq[n] + bqv;
    k[base] = ak[n] + bkv;
    v[base] = av[n] + bvv;
  }
  float bsv = bs[cs];
  int nodex = n0 + wq_ * 4;
  xr[(size_t)(nodex + 0) * 64 + cs] = ax0 + bsv;
  xr[(size_t)(nodex + 1) * 64 + cs] = ax1 + bsv;
  xr[(size_t)(nodex + 2) * 64 + cs] = ax2 + bsv;
  xr[(size_t)(nodex + 3) * 64 + cs] = ax3 + bsv;
}

// ---------------- edge pass 1: ex = exp(q[dst]·(k[src]+eproj)/8), s += ex ----
// one wave per edge; lane = channel
__global__ __launch_bounds__(256) void edge1_kernel(
    const int* __restrict__ ei, const float* __restrict__ ea,
    const float* __restrict__ q, const float* __restrict__ k,
    const float* __restrict__ We, float* __restrict__ ex,
    float* __restrict__ s) {
  const int gid = blockIdx.x * 256 + threadIdx.x;
  const int e = gid >> 6;
  const int lane = gid & 63;
  if (e >= EE) return;
  const int src = ei[e];
  const int dst = ei[EE + e];
  const float a0 = ea[(size_t)e * 4 + 0];
  const float a1 = ea[(size_t)e * 4 + 1];
  const float a2 = ea[(size_t)e * 4 + 2];
  const float a3 = ea[(size_t)e * 4 + 3];
  const float* qrow = q + (size_t)dst * 256;
  const float* krow = k + (size_t)src * 256;
  float acc[4];
  #pragma unroll
  for (int hh = 0; hh < 4; hh++) {
    int c = hh * 64 + lane;
    float eh = a0 * We[c] + a1 * We[256 + c] + a2 * We[512 + c] + a3 * We[768 + c];
    acc[hh] = qrow[c] * (krow[c] + eh);
  }
  #pragma unroll
  for (int hh = 0; hh < 4; hh++) acc[hh] = wsum64(acc[hh]);
  if (lane < 4) {
    float aa = (lane == 0) ? acc[0] : (lane == 1) ? acc[1] : (lane == 2) ? acc[2] : acc[3];
    float exv = expf(aa * 0.125f);  // softmax shift-invariance: no max pass needed
    ex[(size_t)e * 4 + lane] = exv;
    atomicAdd(&s[(size_t)dst * 4 + lane], exv);
  }
}

// ---------------- edge pass 2: agg[dst] += 0.25*sum_h attn_h*(v[src]+eproj) --
__global__ __launch_bounds__(256) void edge2_kernel(
    const int* __restrict__ ei, const float* __restrict__ ea,
    const float* __restrict__ v, const float* __restrict__ We,
    const float* __restrict__ ex, const float* __restrict__ s,
    float* __restrict__ agg) {
  const int gid = blockIdx.x * 256 + threadIdx.x;
  const int e = gid >> 6;
  const int lane = gid & 63;
  if (e >= EE) return;
  const int src = ei[e];
  const int dst = ei[EE + e];
  const float a0 = ea[(size_t)e * 4 + 0];
  const float a1 = ea[(size_t)e * 4 + 1];
  const float a2 = ea[(size_t)e * 4 + 2];
  const float a3 = ea[(size_t)e * 4 + 3];
  float at[4];
  #pragma unroll
  for (int hh = 0; hh < 4; hh++) {
    at[hh] = ex[(size_t)e * 4 + hh] / (s[(size_t)dst * 4 + hh] + 1e-16f);
  }
  const float* vrow = v + (size_t)src * 256;
  float contrib = 0.f;
  #pragma unroll
  for (int hh = 0; hh < 4; hh++) {
    int c = hh * 64 + lane;
    float eh = a0 * We[c] + a1 * We[256 + c] + a2 * We[512 + c] + a3 * We[768 + c];
    contrib += at[hh] * (vrow[c] + eh);
  }
  atomicAdd(&agg[(size_t)dst * 64 + lane], 0.25f * contrib);
}

// ---------------- node update: beta-gate + residual + LN ----------------
__global__ __launch_bounds__(256) void node_kernel(
    const float* __restrict__ agg, const float* __restrict__ xr,
    float* __restrict__ h, const float* __restrict__ Wb,
    const float* __restrict__ lg, const float* __restrict__ lb) {
  const int t = blockIdx.x * 256 + threadIdx.x;
  const int node = t >> 6;
  const int lane = t & 63;
  if (node >= NN) return;
  float o = agg[(size_t)node * 64 + lane];
  float x = xr[(size_t)node * 64 + lane];
  float p = o * Wb[lane] + x * Wb[64 + lane] + (o - x) * Wb[128 + lane];
  p = wsum64(p);
  float beta = 1.0f / (1.0f + expf(-p));
  float hn = beta * x + (1.0f - beta) * o;
  float val = h[(size_t)node * 64 + lane] + hn;
  float s1 = wsum64(val);
  float s2 = wsum64(val * val);
  float m = s1 * (1.0f / 64.0f);
  float var = s2 * (1.0f / 64.0f) - m * m;
  h[(size_t)node * 64 + lane] = (val - m) * rsqrtf(var + 1e-5f) * lg[lane] + lb[lane];
}

// ---------------- head: out = gelu(h@w1+b1)@w2+b2 ----------------
// 32 lanes per node, 8 nodes per block
__global__ __launch_bounds__(256) void head_kernel(
    const float* __restrict__ h, const float* __restrict__ w1,
    const float* __restrict__ b1, const float* __restrict__ w2,
    const float* __restrict__ b2, float* __restrict__ out) {
  const int base_node = blockIdx.x * 8;
  const int nib = threadIdx.x >> 5;  // node in block
  const int c = threadIdx.x & 31;    // hidden col
  __shared__ float hS[8][64];
  #pragma unroll
  for (int i = 0; i < 2; i++) {
    int idx = threadIdx.x + i * 256;
    int nn = idx >> 6, d = idx & 63;
    if (base_node + nn < NN) hS[nn][d] = h[(size_t)(base_node + nn) * 64 + d];
  }
  __syncthreads();
  const int node = base_node + nib;
  if (node < NN) {
    float a = b1[c];
    #pragma unroll 8
    for (int d = 0; d < 64; d++) a += hS[nib][d] * w1[d * 32 + c];
    float g = gelu_exact(a);
    float p0 = g * w2[c * 2 + 0];
    float p1 = g * w2[c * 2 + 1];
    #pragma unroll
    for (int m = 1; m < 32; m <<= 1) {
      p0 += __shfl_xor(p0, m, 64);
      p1 += __shfl_xor(p1, m, 64);
    }
    if (c == 0) {
      out[(size_t)node * 2 + 0] = p0 + b2[0];
      out[(size_t)node * 2 + 1] = p1 + b2[1];
    }
  }
}

extern "C" void kernel_launch(void* const* d_in, const int* in_sizes, int n_in,
                              void* d_out, int out_size, void* d_ws, size_t ws_size,
                              hipStream_t stream) {
  const float* x       = (const float*)d_in[0];
  const int*   ei      = (const int*)d_in[1];
  const float* ea      = (const float*)d_in[2];
  const float* enc_w1  = (const float*)d_in[3];
  const float* enc_b1  = (const float*)d_in[4];
  const float* enc_lng = (const float*)d_in[5];
  const float* enc_lnb = (const float*)d_in[6];
  const float* enc_w2  = (const float*)d_in[7];
  const float* enc_b2  = (const float*)d_in[8];
  const float* Wq      = (const float*)d_in[9];
  const float* bq      = (const float*)d_in[10];
  const float* Wk      = (const float*)d_in[11];
  const float* bk      = (const float*)d_in[12];
  const float* Wv      = (const float*)d_in[13];
  const float* bv      = (const float*)d_in[14];
  const float* We      = (const float*)d_in[15];
  const float* Wskip   = (const float*)d_in[16];
  const float* bskip   = (const float*)d_in[17];
  const float* Wbeta   = (const float*)d_in[18];
  const float* ln_g    = (const float*)d_in[19];
  const float* ln_b    = (const float*)d_in[20];
  const float* hw1     = (const float*)d_in[21];
  const float* hb1     = (const float*)d_in[22];
  const float* hw2     = (const float*)d_in[23];
  const float* hb2     = (const float*)d_in[24];
  float* out = (float*)d_out;

  float* ws  = (float*)d_ws;
  float* h   = ws + OFF_H;
  float* q   = ws + OFF_Q;
  float* k   = ws + OFF_K;
  float* v   = ws + OFF_V;
  float* xr  = ws + OFF_XR;
  float* agg = ws + OFF_AGG;
  float* s   = ws + OFF_S;
  float* ex  = ws + OFF_EX;

  enc_kernel<<<12500, 256, 0, stream>>>(x, enc_w1, enc_b1, enc_lng, enc_lnb,
                                        enc_w2, enc_b2, h);

  for (int l = 0; l < 2; l++) {
    proj_kernel<<<3125, 256, 0, stream>>>(
        h, Wq + (size_t)l * 16384, bq + (size_t)l * 256,
        Wk + (size_t)l * 16384, bk + (size_t)l * 256,
        Wv + (size_t)l * 16384, bv + (size_t)l * 256,
        Wskip + (size_t)l * 4096, bskip + (size_t)l * 64, q, k, v, xr);
    // zero agg [N*64] + s [N*4] (contiguous)
    hipMemsetAsync(agg, 0, (size_t)NN * 68 * sizeof(float), stream);
    edge1_kernel<<<62500, 256, 0, stream>>>(ei, ea, q, k, We + (size_t)l * 1024,
                                            ex, s);
    edge2_kernel<<<62500, 256, 0, stream>>>(ei, ea, v, We + (size_t)l * 1024,
                                            ex, s, agg);
    node_kernel<<<12500, 256, 0, stream>>>(agg, xr, h, Wbeta + (size_t)l * 192,
                                           ln_g + (size_t)l * 64,
                                           ln_b + (size_t)l * 64);
  }

  head_kernel<<<6250, 256, 0, stream>>>(h, hw1, hb1, hw2, hb2, out);
}

// Round 3
// 562.455 us; speedup vs baseline: 1.1563x; 1.1563x over previous
//
#include <hip/hip_runtime.h>
#include <hip/hip_bf16.h>
#include <math.h>

#define NN 50000
#define EE 250000

typedef __attribute__((ext_vector_type(8))) short bf16x8;
typedef __attribute__((ext_vector_type(4))) float f32x4;

__device__ __forceinline__ float wsum64(float v) {
  v += __shfl_xor(v, 1, 64);
  v += __shfl_xor(v, 2, 64);
  v += __shfl_xor(v, 4, 64);
  v += __shfl_xor(v, 8, 64);
  v += __shfl_xor(v, 16, 64);
  v += __shfl_xor(v, 32, 64);
  return v;
}

__device__ __forceinline__ float gelu_exact(float a) {
  return 0.5f * a * (1.0f + erff(a * 0.70710678118654752f));
}

// ---------------- weight converter: Wq/Wk/Wv/Wskip -> bf16 MFMA-B-fragment layout
// Wb element for (layer, ct, f, lane, i): col = ct*16 + (lane&15), k = f*32 + (lane>>4)*8 + i
// 52 col-tiles * 2 k-frags * 64 lanes * 8 elems = 53248 per layer
__global__ __launch_bounds__(256) void convert_wb_kernel(
    const float* __restrict__ Wq, const float* __restrict__ Wk,
    const float* __restrict__ Wv, const float* __restrict__ Ws,
    __hip_bfloat16* __restrict__ Wb) {
  const int tid = blockIdx.x * 256 + threadIdx.x;  // 0 .. 2*53248-1
  const int layer = tid / 53248;
  const int rem = tid % 53248;
  const int i = rem & 7;
  const int l = (rem >> 3) & 63;
  const int fct = rem >> 9;        // ct*2 + f
  const int f = fct & 1;
  const int ct = fct >> 1;
  const int col = ct * 16 + (l & 15);
  const int kk = f * 32 + (l >> 4) * 8 + i;
  float val;
  if (col < 256)      val = Wq[(size_t)layer * 16384 + kk * 256 + col];
  else if (col < 512) val = Wk[(size_t)layer * 16384 + kk * 256 + (col - 256)];
  else if (col < 768) val = Wv[(size_t)layer * 16384 + kk * 256 + (col - 512)];
  else                val = Ws[(size_t)layer * 4096 + kk * 64 + (col - 768)];
  Wb[tid] = __float2bfloat16(val);
}

// ---------------- encoder: h = LN(gelu(x@W1+b1)) @ W2 + b2 (fp32 + bf16 copy)
__global__ __launch_bounds__(256) void enc_kernel(
    const float* __restrict__ x, const float* __restrict__ w1,
    const float* __restrict__ b1, const float* __restrict__ lg,
    const float* __restrict__ lb, const float* __restrict__ w2,
    const float* __restrict__ b2, float* __restrict__ h,
    __hip_bfloat16* __restrict__ hb) {
  const int t = blockIdx.x * 256 + threadIdx.x;
  const int node = t >> 6;
  const int lane = t & 63;
  const int wib = (threadIdx.x >> 6);
  __shared__ float gS[4][64];
  if (node < NN) {
    float a = b1[lane];
    #pragma unroll
    for (int d = 0; d < 6; d++) a += x[(size_t)node * 6 + d] * w1[d * 64 + lane];
    float g = gelu_exact(a);
    float s1 = wsum64(g);
    float s2 = wsum64(g * g);
    float m = s1 * (1.0f / 64.0f);
    float var = s2 * (1.0f / 64.0f) - m * m;
    g = (g - m) * rsqrtf(var + 1e-5f) * lg[lane] + lb[lane];
    gS[wib][lane] = g;
  }
  __syncthreads();
  if (node < NN) {
    float a = b2[lane];
    #pragma unroll 8
    for (int d = 0; d < 64; d++) a += gS[wib][d] * w2[d * 64 + lane];
    h[(size_t)node * 64 + lane] = a;
    hb[(size_t)node * 64 + lane] = __float2bfloat16(a);
  }
}

// ---------------- fused projections via MFMA: q,k,v bf16 [N,256], xr fp32 [N,64]
// block = 256 threads = 4 waves; wave w owns rows n0+16w..+15; loops 52 col-tiles.
__global__ __launch_bounds__(256) void proj_mfma_kernel(
    const __hip_bfloat16* __restrict__ hbf,
    const __hip_bfloat16* __restrict__ Wb,
    const float* __restrict__ bq, const float* __restrict__ bk,
    const float* __restrict__ bv, const float* __restrict__ bs,
    __hip_bfloat16* __restrict__ q, __hip_bfloat16* __restrict__ k,
    __hip_bfloat16* __restrict__ v, float* __restrict__ xr) {
  const int n0 = blockIdx.x * 64;
  const int w = threadIdx.x >> 6;
  const int l = threadIdx.x & 63;
  const int r = l & 15;
  const int g = l >> 4;
  const int arow = n0 + w * 16 + r;

  bf16x8 A0 = {}, A1 = {};
  if (arow < NN) {
    const bf16x8* ap = reinterpret_cast<const bf16x8*>(hbf + (size_t)arow * 64);
    A0 = ap[g];        // k = g*8 .. g*8+7
    A1 = ap[g + 4];    // k = 32 + g*8 ..
  }

  const bf16x8* wb = reinterpret_cast<const bf16x8*>(Wb);
  const int nbase = n0 + w * 16 + g * 4;

  for (int ct = 0; ct < 52; ++ct) {
    bf16x8 B0 = wb[(ct * 2 + 0) * 64 + l];
    bf16x8 B1 = wb[(ct * 2 + 1) * 64 + l];
    f32x4 acc = {0.f, 0.f, 0.f, 0.f};
    acc = __builtin_amdgcn_mfma_f32_16x16x32_bf16(A0, B0, acc, 0, 0, 0);
    acc = __builtin_amdgcn_mfma_f32_16x16x32_bf16(A1, B1, acc, 0, 0, 0);
    const int col = ct * 16 + r;   // C/D: col = lane&15, row = (lane>>4)*4 + i
    if (ct < 48) {
      __hip_bfloat16* dstp;
      const float* bias;
      int c;
      if (ct < 16)      { dstp = q; bias = bq; c = col; }
      else if (ct < 32) { dstp = k; bias = bk; c = col - 256; }
      else              { dstp = v; bias = bv; c = col - 512; }
      const float bb = bias[c];
      #pragma unroll
      for (int i = 0; i < 4; ++i) {
        const int node = nbase + i;
        if (node < NN) dstp[(size_t)node * 256 + c] = __float2bfloat16(acc[i] + bb);
      }
    } else {
      const int c = col - 768;
      const float bb = bs[c];
      #pragma unroll
      for (int i = 0; i < 4; ++i) {
        const int node = nbase + i;
        if (node < NN) xr[(size_t)node * 64 + c] = acc[i] + bb;
      }
    }
  }
}

// ---------------- edge pass 1: ex = exp(q[dst]·(k[src]+eproj)/8), s += ex ----
__global__ __launch_bounds__(256) void edge1_kernel(
    const int* __restrict__ ei, const float* __restrict__ ea,
    const __hip_bfloat16* __restrict__ q, const __hip_bfloat16* __restrict__ k,
    const float* __restrict__ We, float* __restrict__ ex,
    float* __restrict__ s) {
  const int gid = blockIdx.x * 256 + threadIdx.x;
  const int e = gid >> 6;
  const int lane = gid & 63;
  if (e >= EE) return;
  const int src = ei[e];
  const int dst = ei[EE + e];
  const float a0 = ea[(size_t)e * 4 + 0];
  const float a1 = ea[(size_t)e * 4 + 1];
  const float a2 = ea[(size_t)e * 4 + 2];
  const float a3 = ea[(size_t)e * 4 + 3];
  const __hip_bfloat16* qrow = q + (size_t)dst * 256;
  const __hip_bfloat16* krow = k + (size_t)src * 256;
  float acc[4];
  #pragma unroll
  for (int hh = 0; hh < 4; hh++) {
    int c = hh * 64 + lane;
    float eh = a0 * We[c] + a1 * We[256 + c] + a2 * We[512 + c] + a3 * We[768 + c];
    acc[hh] = __bfloat162float(qrow[c]) * (__bfloat162float(krow[c]) + eh);
  }
  #pragma unroll
  for (int hh = 0; hh < 4; hh++) acc[hh] = wsum64(acc[hh]);
  if (lane < 4) {
    float aa = (lane == 0) ? acc[0] : (lane == 1) ? acc[1] : (lane == 2) ? acc[2] : acc[3];
    float exv = expf(aa * 0.125f);  // softmax shift-invariance: no max pass needed
    ex[(size_t)e * 4 + lane] = exv;
    atomicAdd(&s[(size_t)dst * 4 + lane], exv);
  }
}

// ---------------- edge pass 2: agg[dst] += 0.25*sum_h attn_h*(v[src]+eproj) --
__global__ __launch_bounds__(256) void edge2_kernel(
    const int* __restrict__ ei, const float* __restrict__ ea,
    const __hip_bfloat16* __restrict__ v, const float* __restrict__ We,
    const float* __restrict__ ex, const float* __restrict__ s,
    float* __restrict__ agg) {
  const int gid = blockIdx.x * 256 + threadIdx.x;
  const int e = gid >> 6;
  const int lane = gid & 63;
  if (e >= EE) return;
  const int src = ei[e];
  const int dst = ei[EE + e];
  const float a0 = ea[(size_t)e * 4 + 0];
  const float a1 = ea[(size_t)e * 4 + 1];
  const float a2 = ea[(size_t)e * 4 + 2];
  const float a3 = ea[(size_t)e * 4 + 3];
  float at[4];
  #pragma unroll
  for (int hh = 0; hh < 4; hh++) {
    at[hh] = ex[(size_t)e * 4 + hh] / (s[(size_t)dst * 4 + hh] + 1e-16f);
  }
  const __hip_bfloat16* vrow = v + (size_t)src * 256;
  float contrib = 0.f;
  #pragma unroll
  for (int hh = 0; hh < 4; hh++) {
    int c = hh * 64 + lane;
    float eh = a0 * We[c] + a1 * We[256 + c] + a2 * We[512 + c] + a3 * We[768 + c];
    contrib += at[hh] * (__bfloat162float(vrow[c]) + eh);
  }
  atomicAdd(&agg[(size_t)dst * 64 + lane], 0.25f * contrib);
}

// ---------------- node update: beta-gate + residual + LN ----------------
__global__ __launch_bounds__(256) void node_kernel(
    const float* __restrict__ agg, const float* __restrict__ xr,
    float* __restrict__ h, __hip_bfloat16* __restrict__ hb,
    const float* __restrict__ Wb,
    const float* __restrict__ lg, const float* __restrict__ lb) {
  const int t = blockIdx.x * 256 + threadIdx.x;
  const int node = t >> 6;
  const int lane = t & 63;
  if (node >= NN) return;
  float o = agg[(size_t)node * 64 + lane];
  float x = xr[(size_t)node * 64 + lane];
  float p = o * Wb[lane] + x * Wb[64 + lane] + (o - x) * Wb[128 + lane];
  p = wsum64(p);
  float beta = 1.0f / (1.0f + expf(-p));
  float hn = beta * x + (1.0f - beta) * o;
  float val = h[(size_t)node * 64 + lane] + hn;
  float s1 = wsum64(val);
  float s2 = wsum64(val * val);
  float m = s1 * (1.0f / 64.0f);
  float var = s2 * (1.0f / 64.0f) - m * m;
  float res = (val - m) * rsqrtf(var + 1e-5f) * lg[lane] + lb[lane];
  h[(size_t)node * 64 + lane] = res;
  hb[(size_t)node * 64 + lane] = __float2bfloat16(res);
}

// ---------------- head: out = gelu(h@w1+b1)@w2+b2 ----------------
__global__ __launch_bounds__(256) void head_kernel(
    const float* __restrict__ h, const float* __restrict__ w1,
    const float* __restrict__ b1, const float* __restrict__ w2,
    const float* __restrict__ b2, float* __restrict__ out) {
  const int base_node = blockIdx.x * 8;
  const int nib = threadIdx.x >> 5;
  const int c = threadIdx.x & 31;
  __shared__ float hS[8][64];
  #pragma unroll
  for (int i = 0; i < 2; i++) {
    int idx = threadIdx.x + i * 256;
    int nn = idx >> 6, d = idx & 63;
    if (base_node + nn < NN) hS[nn][d] = h[(size_t)(base_node + nn) * 64 + d];
  }
  __syncthreads();
  const int node = base_node + nib;
  if (node < NN) {
    float a = b1[c];
    #pragma unroll 8
    for (int d = 0; d < 64; d++) a += hS[nib][d] * w1[d * 32 + c];
    float g = gelu_exact(a);
    float p0 = g * w2[c * 2 + 0];
    float p1 = g * w2[c * 2 + 1];
    #pragma unroll
    for (int m = 1; m < 32; m <<= 1) {
      p0 += __shfl_xor(p0, m, 64);
      p1 += __shfl_xor(p1, m, 64);
    }
    if (c == 0) {
      out[(size_t)node * 2 + 0] = p0 + b2[0];
      out[(size_t)node * 2 + 1] = p1 + b2[1];
    }
  }
}

extern "C" void kernel_launch(void* const* d_in, const int* in_sizes, int n_in,
                              void* d_out, int out_size, void* d_ws, size_t ws_size,
                              hipStream_t stream) {
  const float* x       = (const float*)d_in[0];
  const int*   ei      = (const int*)d_in[1];
  const float* ea      = (const float*)d_in[2];
  const float* enc_w1  = (const float*)d_in[3];
  const float* enc_b1  = (const float*)d_in[4];
  const float* enc_lng = (const float*)d_in[5];
  const float* enc_lnb = (const float*)d_in[6];
  const float* enc_w2  = (const float*)d_in[7];
  const float* enc_b2  = (const float*)d_in[8];
  const float* Wq      = (const float*)d_in[9];
  const float* bq      = (const float*)d_in[10];
  const float* Wk      = (const float*)d_in[11];
  const float* bk      = (const float*)d_in[12];
  const float* Wv      = (const float*)d_in[13];
  const float* bv      = (const float*)d_in[14];
  const float* We      = (const float*)d_in[15];
  const float* Wskip   = (const float*)d_in[16];
  const float* bskip   = (const float*)d_in[17];
  const float* Wbeta   = (const float*)d_in[18];
  const float* ln_g    = (const float*)d_in[19];
  const float* ln_b    = (const float*)d_in[20];
  const float* hw1     = (const float*)d_in[21];
  const float* hb1     = (const float*)d_in[22];
  const float* hw2     = (const float*)d_in[23];
  const float* hb2     = (const float*)d_in[24];
  float* out = (float*)d_out;

  float* ws  = (float*)d_ws;
  float* h   = ws;                         // NN*64 fp32
  float* xr  = h + (size_t)NN * 64;        // NN*64 fp32
  float* agg = xr + (size_t)NN * 64;       // NN*64 fp32 (zeroed per layer)
  float* s   = agg + (size_t)NN * 64;      // NN*4  fp32 (zeroed with agg)
  float* ex  = s + (size_t)NN * 4;         // EE*4  fp32
  __hip_bfloat16* hb = (__hip_bfloat16*)(ex + (size_t)EE * 4);  // NN*64
  __hip_bfloat16* qb = hb + (size_t)NN * 64;                    // NN*256
  __hip_bfloat16* kb = qb + (size_t)NN * 256;                   // NN*256
  __hip_bfloat16* vb = kb + (size_t)NN * 256;                   // NN*256
  __hip_bfloat16* Wb = vb + (size_t)NN * 256;                   // 2*53248

  convert_wb_kernel<<<416, 256, 0, stream>>>(Wq, Wk, Wv, Wskip, Wb);
  enc_kernel<<<12500, 256, 0, stream>>>(x, enc_w1, enc_b1, enc_lng, enc_lnb,
                                        enc_w2, enc_b2, h, hb);

  for (int l = 0; l < 2; l++) {
    proj_mfma_kernel<<<782, 256, 0, stream>>>(
        hb, Wb + (size_t)l * 53248,
        bq + (size_t)l * 256, bk + (size_t)l * 256, bv + (size_t)l * 256,
        bskip + (size_t)l * 64, qb, kb, vb, xr);
    hipMemsetAsync(agg, 0, (size_t)NN * 68 * sizeof(float), stream);
    edge1_kernel<<<62500, 256, 0, stream>>>(ei, ea, qb, kb, We + (size_t)l * 1024,
                                            ex, s);
    edge2_kernel<<<62500, 256, 0, stream>>>(ei, ea, vb, We + (size_t)l * 1024,
                                            ex, s, agg);
    node_kernel<<<12500, 256, 0, stream>>>(agg, xr, h, hb, Wbeta + (size_t)l * 192,
                                           ln_g + (size_t)l * 64,
                                           ln_b + (size_t)l * 64);
  }

  head_kernel<<<6250, 256, 0, stream>>>(h, hw1, hb1, hw2, hb2, out);
}

// Round 4
// 499.488 us; speedup vs baseline: 1.3021x; 1.1261x over previous
//
#include <hip/hip_runtime.h>
#include <hip/hip_bf16.h>
#include <math.h>

#define NN 50000
#define EE 250000
#define EDGE_BLOCKS 2048
#define EDGE_WAVES (EDGE_BLOCKS * 4)

typedef __attribute__((ext_vector_type(8))) short bf16x8;
typedef __attribute__((ext_vector_type(4))) float f32x4;

__device__ __forceinline__ float wsum64(float v) {
  v += __shfl_xor(v, 1, 64);
  v += __shfl_xor(v, 2, 64);
  v += __shfl_xor(v, 4, 64);
  v += __shfl_xor(v, 8, 64);
  v += __shfl_xor(v, 16, 64);
  v += __shfl_xor(v, 32, 64);
  return v;
}

__device__ __forceinline__ float gelu_exact(float a) {
  return 0.5f * a * (1.0f + erff(a * 0.70710678118654752f));
}

// convert 4 packed bf16 (8B as uint2) to 4 floats
__device__ __forceinline__ void bf4_to_f(const uint2 u, float* f) {
  f[0] = __uint_as_float(u.x << 16);
  f[1] = __uint_as_float(u.x & 0xffff0000u);
  f[2] = __uint_as_float(u.y << 16);
  f[3] = __uint_as_float(u.y & 0xffff0000u);
}

// ---------------- weight converter: Wq/Wk/Wv/Wskip -> bf16 MFMA-B-fragment layout
__global__ __launch_bounds__(256) void convert_wb_kernel(
    const float* __restrict__ Wq, const float* __restrict__ Wk,
    const float* __restrict__ Wv, const float* __restrict__ Ws,
    __hip_bfloat16* __restrict__ Wb) {
  const int tid = blockIdx.x * 256 + threadIdx.x;  // 0 .. 2*53248-1
  const int layer = tid / 53248;
  const int rem = tid % 53248;
  const int i = rem & 7;
  const int l = (rem >> 3) & 63;
  const int fct = rem >> 9;        // ct*2 + f
  const int f = fct & 1;
  const int ct = fct >> 1;
  const int col = ct * 16 + (l & 15);
  const int kk = f * 32 + (l >> 4) * 8 + i;
  float val;
  if (col < 256)      val = Wq[(size_t)layer * 16384 + kk * 256 + col];
  else if (col < 512) val = Wk[(size_t)layer * 16384 + kk * 256 + (col - 256)];
  else if (col < 768) val = Wv[(size_t)layer * 16384 + kk * 256 + (col - 512)];
  else                val = Ws[(size_t)layer * 4096 + kk * 64 + (col - 768)];
  Wb[tid] = __float2bfloat16(val);
}

// ---------------- encoder ----------------
__global__ __launch_bounds__(256) void enc_kernel(
    const float* __restrict__ x, const float* __restrict__ w1,
    const float* __restrict__ b1, const float* __restrict__ lg,
    const float* __restrict__ lb, const float* __restrict__ w2,
    const float* __restrict__ b2, float* __restrict__ h,
    __hip_bfloat16* __restrict__ hb) {
  const int t = blockIdx.x * 256 + threadIdx.x;
  const int node = t >> 6;
  const int lane = t & 63;
  const int wib = (threadIdx.x >> 6);
  __shared__ float gS[4][64];
  if (node < NN) {
    float a = b1[lane];
    #pragma unroll
    for (int d = 0; d < 6; d++) a += x[(size_t)node * 6 + d] * w1[d * 64 + lane];
    float g = gelu_exact(a);
    float s1 = wsum64(g);
    float s2 = wsum64(g * g);
    float m = s1 * (1.0f / 64.0f);
    float var = s2 * (1.0f / 64.0f) - m * m;
    g = (g - m) * rsqrtf(var + 1e-5f) * lg[lane] + lb[lane];
    gS[wib][lane] = g;
  }
  __syncthreads();
  if (node < NN) {
    float a = b2[lane];
    #pragma unroll 8
    for (int d = 0; d < 64; d++) a += gS[wib][d] * w2[d * 64 + lane];
    h[(size_t)node * 64 + lane] = a;
    hb[(size_t)node * 64 + lane] = __float2bfloat16(a);
  }
}

// ---------------- fused projections via MFMA ----------------
// q is written PRE-SCALED by 0.125 (1/sqrt(C), exact in bf16).
__global__ __launch_bounds__(256) void proj_mfma_kernel(
    const __hip_bfloat16* __restrict__ hbf,
    const __hip_bfloat16* __restrict__ Wb,
    const float* __restrict__ bq, const float* __restrict__ bk,
    const float* __restrict__ bv, const float* __restrict__ bs,
    __hip_bfloat16* __restrict__ q, __hip_bfloat16* __restrict__ k,
    __hip_bfloat16* __restrict__ v, float* __restrict__ xr) {
  const int n0 = blockIdx.x * 64;
  const int w = threadIdx.x >> 6;
  const int l = threadIdx.x & 63;
  const int r = l & 15;
  const int g = l >> 4;
  const int arow = n0 + w * 16 + r;

  bf16x8 A0 = {}, A1 = {};
  if (arow < NN) {
    const bf16x8* ap = reinterpret_cast<const bf16x8*>(hbf + (size_t)arow * 64);
    A0 = ap[g];
    A1 = ap[g + 4];
  }

  const bf16x8* wb = reinterpret_cast<const bf16x8*>(Wb);
  const int nbase = n0 + w * 16 + g * 4;

  for (int ct = 0; ct < 52; ++ct) {
    bf16x8 B0 = wb[(ct * 2 + 0) * 64 + l];
    bf16x8 B1 = wb[(ct * 2 + 1) * 64 + l];
    f32x4 acc = {0.f, 0.f, 0.f, 0.f};
    acc = __builtin_amdgcn_mfma_f32_16x16x32_bf16(A0, B0, acc, 0, 0, 0);
    acc = __builtin_amdgcn_mfma_f32_16x16x32_bf16(A1, B1, acc, 0, 0, 0);
    const int col = ct * 16 + r;   // C/D: col = lane&15, row = (lane>>4)*4 + i
    if (ct < 48) {
      __hip_bfloat16* dstp;
      const float* bias;
      int c;
      float scale = 1.0f;
      if (ct < 16)      { dstp = q; bias = bq; c = col; scale = 0.125f; }
      else if (ct < 32) { dstp = k; bias = bk; c = col - 256; }
      else              { dstp = v; bias = bv; c = col - 512; }
      const float bb = bias[c];
      #pragma unroll
      for (int i = 0; i < 4; ++i) {
        const int node = nbase + i;
        if (node < NN)
          dstp[(size_t)node * 256 + c] = __float2bfloat16((acc[i] + bb) * scale);
      }
    } else {
      const int c = col - 768;
      const float bb = bs[c];
      #pragma unroll
      for (int i = 0; i < 4; ++i) {
        const int node = nbase + i;
        if (node < NN) xr[(size_t)node * 64 + c] = acc[i] + bb;
      }
    }
  }
}

// ---------------- edge pass 1: ex = exp(q[dst]·(k[src]+eproj)), s += ex ------
// grid-stride persistent waves; lane owns channels lane*4..lane*4+3 (head lane>>4).
// q comes pre-scaled by 1/sqrt(C).
__global__ __launch_bounds__(256) void edge1_kernel(
    const int* __restrict__ ei, const float* __restrict__ ea,
    const __hip_bfloat16* __restrict__ qb, const __hip_bfloat16* __restrict__ kb,
    const float* __restrict__ We, float* __restrict__ ex,
    float* __restrict__ s) {
  const int wid = (blockIdx.x * 256 + threadIdx.x) >> 6;
  const int lane = threadIdx.x & 63;
  const int c0 = lane * 4;
  const int hd = lane >> 4;
  const ushort* q = reinterpret_cast<const ushort*>(qb);
  const ushort* k = reinterpret_cast<const ushort*>(kb);
  const float4* ea4 = reinterpret_cast<const float4*>(ea);

  // hoist edge-weight columns for this lane's 4 channels (16 regs)
  float4 w0 = *reinterpret_cast<const float4*>(We + 0 * 256 + c0);
  float4 w1 = *reinterpret_cast<const float4*>(We + 1 * 256 + c0);
  float4 w2 = *reinterpret_cast<const float4*>(We + 2 * 256 + c0);
  float4 w3 = *reinterpret_cast<const float4*>(We + 3 * 256 + c0);

  int e = wid;
  if (e >= EE) return;
  int src = ei[e], dst = ei[EE + e];
  float4 av = ea4[e];
  while (true) {
    const int en = e + EDGE_WAVES;
    int src_n = 0, dst_n = 0;
    float4 av_n = {0.f, 0.f, 0.f, 0.f};
    if (en < EE) { src_n = ei[en]; dst_n = ei[EE + en]; av_n = ea4[en]; }

    uint2 qu = *reinterpret_cast<const uint2*>(q + (size_t)dst * 256 + c0);
    uint2 ku = *reinterpret_cast<const uint2*>(k + (size_t)src * 256 + c0);
    float qf[4], kf[4];
    bf4_to_f(qu, qf);
    bf4_to_f(ku, kf);
    float eh0 = av.x * w0.x + av.y * w1.x + av.z * w2.x + av.w * w3.x;
    float eh1 = av.x * w0.y + av.y * w1.y + av.z * w2.y + av.w * w3.y;
    float eh2 = av.x * w0.z + av.y * w1.z + av.z * w2.z + av.w * w3.z;
    float eh3 = av.x * w0.w + av.y * w1.w + av.z * w2.w + av.w * w3.w;
    float acc = qf[0] * (kf[0] + eh0) + qf[1] * (kf[1] + eh1) +
                qf[2] * (kf[2] + eh2) + qf[3] * (kf[3] + eh3);
    acc += __shfl_xor(acc, 1, 64);
    acc += __shfl_xor(acc, 2, 64);
    acc += __shfl_xor(acc, 4, 64);
    acc += __shfl_xor(acc, 8, 64);
    if ((lane & 15) == 0) {
      float exv = __expf(acc);   // softmax shift-invariance: no max pass needed
      ex[(size_t)e * 4 + hd] = exv;
      atomicAdd(&s[(size_t)dst * 4 + hd], exv);
    }
    if (en >= EE) break;
    e = en; src = src_n; dst = dst_n; av = av_n;
  }
}

// ---------------- edge pass 2: agg[dst] += 0.25*sum_h attn_h*(v[src]+eproj) --
__global__ __launch_bounds__(256) void edge2_kernel(
    const int* __restrict__ ei, const float* __restrict__ ea,
    const __hip_bfloat16* __restrict__ vb, const float* __restrict__ We,
    const float* __restrict__ ex, const float* __restrict__ s,
    float* __restrict__ agg) {
  const int wid = (blockIdx.x * 256 + threadIdx.x) >> 6;
  const int lane = threadIdx.x & 63;
  const int c0 = lane * 4;
  const int hd = lane >> 4;
  const ushort* v = reinterpret_cast<const ushort*>(vb);
  const float4* ea4 = reinterpret_cast<const float4*>(ea);

  float4 w0 = *reinterpret_cast<const float4*>(We + 0 * 256 + c0);
  float4 w1 = *reinterpret_cast<const float4*>(We + 1 * 256 + c0);
  float4 w2 = *reinterpret_cast<const float4*>(We + 2 * 256 + c0);
  float4 w3 = *reinterpret_cast<const float4*>(We + 3 * 256 + c0);

  int e = wid;
  if (e >= EE) return;
  int src = ei[e], dst = ei[EE + e];
  float4 av = ea4[e];
  while (true) {
    const int en = e + EDGE_WAVES;
    int src_n = 0, dst_n = 0;
    float4 av_n = {0.f, 0.f, 0.f, 0.f};
    if (en < EE) { src_n = ei[en]; dst_n = ei[EE + en]; av_n = ea4[en]; }

    // per-lane head attn weight (4 unique addresses per wave -> broadcast-ish)
    float exh = ex[(size_t)e * 4 + hd];
    float sh = s[(size_t)dst * 4 + hd];
    float at = 0.25f * exh / (sh + 1e-16f);

    uint2 vu = *reinterpret_cast<const uint2*>(v + (size_t)src * 256 + c0);
    float vf[4];
    bf4_to_f(vu, vf);
    float eh0 = av.x * w0.x + av.y * w1.x + av.z * w2.x + av.w * w3.x;
    float eh1 = av.x * w0.y + av.y * w1.y + av.z * w2.y + av.w * w3.y;
    float eh2 = av.x * w0.z + av.y * w1.z + av.z * w2.z + av.w * w3.z;
    float eh3 = av.x * w0.w + av.y * w1.w + av.z * w2.w + av.w * w3.w;
    float ct0 = at * (vf[0] + eh0);
    float ct1 = at * (vf[1] + eh1);
    float ct2 = at * (vf[2] + eh2);
    float ct3 = at * (vf[3] + eh3);
    // sum over the 4 head-groups (lanes l, l+16, l+32, l+48)
    ct0 += __shfl_xor(ct0, 16, 64); ct0 += __shfl_xor(ct0, 32, 64);
    ct1 += __shfl_xor(ct1, 16, 64); ct1 += __shfl_xor(ct1, 32, 64);
    ct2 += __shfl_xor(ct2, 16, 64); ct2 += __shfl_xor(ct2, 32, 64);
    ct3 += __shfl_xor(ct3, 16, 64); ct3 += __shfl_xor(ct3, 32, 64);
    // each lane commits one dword: channel (lane&15)*4 + hd  (static selects)
    float c01 = (hd & 1) ? ct1 : ct0;
    float c23 = (hd & 1) ? ct3 : ct2;
    float cj = (hd & 2) ? c23 : c01;
    atomicAdd(&agg[(size_t)dst * 64 + (lane & 15) * 4 + hd], cj);
    if (en >= EE) break;
    e = en; src = src_n; dst = dst_n; av = av_n;
  }
}

// ---------------- node update: beta-gate + residual + LN ----------------
__global__ __launch_bounds__(256) void node_kernel(
    const float* __restrict__ agg, const float* __restrict__ xr,
    float* __restrict__ h, __hip_bfloat16* __restrict__ hb,
    const float* __restrict__ Wb,
    const float* __restrict__ lg, const float* __restrict__ lb) {
  const int t = blockIdx.x * 256 + threadIdx.x;
  const int node = t >> 6;
  const int lane = t & 63;
  if (node >= NN) return;
  float o = agg[(size_t)node * 64 + lane];
  float x = xr[(size_t)node * 64 + lane];
  float p = o * Wb[lane] + x * Wb[64 + lane] + (o - x) * Wb[128 + lane];
  p = wsum64(p);
  float beta = 1.0f / (1.0f + expf(-p));
  float hn = beta * x + (1.0f - beta) * o;
  float val = h[(size_t)node * 64 + lane] + hn;
  float s1 = wsum64(val);
  float s2 = wsum64(val * val);
  float m = s1 * (1.0f / 64.0f);
  float var = s2 * (1.0f / 64.0f) - m * m;
  float res = (val - m) * rsqrtf(var + 1e-5f) * lg[lane] + lb[lane];
  h[(size_t)node * 64 + lane] = res;
  hb[(size_t)node * 64 + lane] = __float2bfloat16(res);
}

// ---------------- head ----------------
__global__ __launch_bounds__(256) void head_kernel(
    const float* __restrict__ h, const float* __restrict__ w1,
    const float* __restrict__ b1, const float* __restrict__ w2,
    const float* __restrict__ b2, float* __restrict__ out) {
  const int base_node = blockIdx.x * 8;
  const int nib = threadIdx.x >> 5;
  const int c = threadIdx.x & 31;
  __shared__ float hS[8][64];
  #pragma unroll
  for (int i = 0; i < 2; i++) {
    int idx = threadIdx.x + i * 256;
    int nn = idx >> 6, d = idx & 63;
    if (base_node + nn < NN) hS[nn][d] = h[(size_t)(base_node + nn) * 64 + d];
  }
  __syncthreads();
  const int node = base_node + nib;
  if (node < NN) {
    float a = b1[c];
    #pragma unroll 8
    for (int d = 0; d < 64; d++) a += hS[nib][d] * w1[d * 32 + c];
    float g = gelu_exact(a);
    float p0 = g * w2[c * 2 + 0];
    float p1 = g * w2[c * 2 + 1];
    #pragma unroll
    for (int m = 1; m < 32; m <<= 1) {
      p0 += __shfl_xor(p0, m, 64);
      p1 += __shfl_xor(p1, m, 64);
    }
    if (c == 0) {
      out[(size_t)node * 2 + 0] = p0 + b2[0];
      out[(size_t)node * 2 + 1] = p1 + b2[1];
    }
  }
}

extern "C" void kernel_launch(void* const* d_in, const int* in_sizes, int n_in,
                              void* d_out, int out_size, void* d_ws, size_t ws_size,
                              hipStream_t stream) {
  const float* x       = (const float*)d_in[0];
  const int*   ei      = (const int*)d_in[1];
  const float* ea      = (const float*)d_in[2];
  const float* enc_w1  = (const float*)d_in[3];
  const float* enc_b1  = (const float*)d_in[4];
  const float* enc_lng = (const float*)d_in[5];
  const float* enc_lnb = (const float*)d_in[6];
  const float* enc_w2  = (const float*)d_in[7];
  const float* enc_b2  = (const float*)d_in[8];
  const float* Wq      = (const float*)d_in[9];
  const float* bq      = (const float*)d_in[10];
  const float* Wk      = (const float*)d_in[11];
  const float* bk      = (const float*)d_in[12];
  const float* Wv      = (const float*)d_in[13];
  const float* bv      = (const float*)d_in[14];
  const float* We      = (const float*)d_in[15];
  const float* Wskip   = (const float*)d_in[16];
  const float* bskip   = (const float*)d_in[17];
  const float* Wbeta   = (const float*)d_in[18];
  const float* ln_g    = (const float*)d_in[19];
  const float* ln_b    = (const float*)d_in[20];
  const float* hw1     = (const float*)d_in[21];
  const float* hb1     = (const float*)d_in[22];
  const float* hw2     = (const float*)d_in[23];
  const float* hb2     = (const float*)d_in[24];
  float* out = (float*)d_out;

  float* ws  = (float*)d_ws;
  float* h   = ws;                         // NN*64 fp32
  float* xr  = h + (size_t)NN * 64;        // NN*64 fp32
  float* agg = xr + (size_t)NN * 64;       // NN*64 fp32 (zeroed per layer)
  float* s   = agg + (size_t)NN * 64;      // NN*4  fp32 (zeroed with agg)
  float* ex  = s + (size_t)NN * 4;         // EE*4  fp32
  __hip_bfloat16* hb = (__hip_bfloat16*)(ex + (size_t)EE * 4);  // NN*64
  __hip_bfloat16* qb = hb + (size_t)NN * 64;                    // NN*256
  __hip_bfloat16* kb = qb + (size_t)NN * 256;                   // NN*256
  __hip_bfloat16* vb = kb + (size_t)NN * 256;                   // NN*256
  __hip_bfloat16* Wb = vb + (size_t)NN * 256;                   // 2*53248

  convert_wb_kernel<<<416, 256, 0, stream>>>(Wq, Wk, Wv, Wskip, Wb);
  enc_kernel<<<12500, 256, 0, stream>>>(x, enc_w1, enc_b1, enc_lng, enc_lnb,
                                        enc_w2, enc_b2, h, hb);

  for (int l = 0; l < 2; l++) {
    proj_mfma_kernel<<<782, 256, 0, stream>>>(
        hb, Wb + (size_t)l * 53248,
        bq + (size_t)l * 256, bk + (size_t)l * 256, bv + (size_t)l * 256,
        bskip + (size_t)l * 64, qb, kb, vb, xr);
    hipMemsetAsync(agg, 0, (size_t)NN * 68 * sizeof(float), stream);
    edge1_kernel<<<EDGE_BLOCKS, 256, 0, stream>>>(ei, ea, qb, kb,
                                                  We + (size_t)l * 1024, ex, s);
    edge2_kernel<<<EDGE_BLOCKS, 256, 0, stream>>>(ei, ea, vb,
                                                  We + (size_t)l * 1024, ex, s, agg);
    node_kernel<<<12500, 256, 0, stream>>>(agg, xr, h, hb, Wbeta + (size_t)l * 192,
                                           ln_g + (size_t)l * 64,
                                           ln_b + (size_t)l * 64);
  }

  head_kernel<<<6250, 256, 0, stream>>>(h, hw1, hb1, hw2, hb2, out);
}